// Round 17
// baseline (289.136 us; speedup 1.0000x reference)
//
#include <hip/hip_runtime.h>
#include <hip/hip_bf16.h>
#include <cstddef>
#include <cstdint>

#define NB 256
#define NS 20
#define NL 512
#define ND 128
#define NH 768
#define ROWE (NS*(ND+NH))   // 17920 floats per output row

typedef __attribute__((ext_vector_type(4))) float  f32x4;
typedef __attribute__((ext_vector_type(8))) short  bf16x8;
typedef __attribute__((ext_vector_type(4))) unsigned short ushort4v;

#define MFMA16 __builtin_amdgcn_mfma_f32_16x16x32_bf16

__device__ __forceinline__ unsigned short bf16_rne(float v){
    unsigned u = __builtin_bit_cast(unsigned, v);
    u = (u + 0x7fffu + ((u>>16)&1u)) >> 16;
    return (unsigned short)u;
}
__device__ __forceinline__ float bf16f(unsigned short h){
    unsigned u = ((unsigned)h)<<16;
    return __builtin_bit_cast(float, u);
}
// LDS-only barrier (no vmcnt drain): global loads stay in flight.
__device__ __forceinline__ void bar_lds(){
    asm volatile("s_waitcnt lgkmcnt(0)" ::: "memory");
    __builtin_amdgcn_s_barrier();
}

// ---------------------------------------------------------------------------
// K1: se = embs[skills[b]] -> out (concat left part);  q = se @ W -> bf16
// hi/lo arrays in ws. 256 blocks x 256 threads; wave w owns s in [5w,5w+5).
// ---------------------------------------------------------------------------
extern "C" __global__ __launch_bounds__(256)
void k1_q(const int* __restrict__ skills, const float* __restrict__ embs,
          const float* __restrict__ W,
          unsigned short* __restrict__ qhi, unsigned short* __restrict__ qlo,
          float* __restrict__ out)
{
    __shared__ float se[NS*ND];
    __shared__ int   sk[NS];
    const int b = blockIdx.x, t = threadIdx.x;
    if (t < NS) sk[t] = skills[b*NS + t];
    __syncthreads();
    for (int idx = t; idx < NS*ND; idx += 256) {
        const int s = idx >> 7, d = idx & (ND-1);
        const float v = embs[(size_t)sk[s]*ND + d];
        se[idx] = v;
        out[(size_t)b*ROWE + (size_t)s*(ND+NH) + d] = v;
    }
    __syncthreads();

    const int w = t >> 6, lane = t & 63;
    float acc[5][12];
    #pragma unroll
    for (int i = 0; i < 5; ++i)
        #pragma unroll
        for (int c = 0; c < 12; ++c) acc[i][c] = 0.f;

    const float* Wl = W + lane;
    for (int d4 = 0; d4 < ND/4; ++d4) {
        f32x4 sv[5];
        #pragma unroll
        for (int i = 0; i < 5; ++i)
            sv[i] = *(const f32x4*)&se[(5*w + i)*ND + 4*d4];
        #pragma unroll
        for (int r = 0; r < 4; ++r) {
            const float* wr = Wl + (size_t)(4*d4 + r)*NH;
            float wv[12];
            #pragma unroll
            for (int c = 0; c < 12; ++c) wv[c] = wr[64*c];
            #pragma unroll
            for (int i = 0; i < 5; ++i) {
                const float s_ = sv[i][r];
                #pragma unroll
                for (int c = 0; c < 12; ++c) acc[i][c] += s_*wv[c];
            }
        }
    }
    #pragma unroll
    for (int i = 0; i < 5; ++i)
        #pragma unroll
        for (int c = 0; c < 12; ++c) {
            const size_t idx = ((size_t)b*NS + 5*w + i)*NH + lane + 64*c;
            const float v = acc[i][c];
            const unsigned short hh = bf16_rne(v);
            qhi[idx] = hh;
            qlo[idx] = bf16_rne(v - bf16f(hh));
        }
}

// ---------------------------------------------------------------------------
// K2F: fused flash partial over an l-range of 256.  Grid (NB,2) split by l.
// 512 threads (8 waves); wave w: st = w&1 (QK s-tile), kq = w>>1 (k-quarter).
//
// R17: NO desc LDS staging.  QK reads A-fragments directly from global as
// f32 (convert to bf16 hi/lo in-register — R16-proven QK); PV re-reads the
// same tile from global, L2/L3-hot (second read of a just-streamed 98 KB/CU
// tile does not touch HBM — R5 evidence), with EXACT f32 math (no
// conversions).  LDS holds only scr/p/f (8 KB) -> occupancy VGPR-bound;
// 2 LDS-only barriers per tile; every desc load is an independent global
// read the compiler pipelines across 16 slipping waves.  q hoisted (R14).
//
// Per 16-row tile (16/block):
//   QK MFMA (A from global, q in regs) + scr | B | kq0: reduce + online
//   softmax -> p_lds2 (f32) / f_lds | B | PV: thread (slot=t%96, sq=t/96<5)
//   owns h = {4slot..+3, 384+4slot..+3}, s = 4sq+j; 2 global b128 per l.
// Outputs UNNORMALIZED Opart + (m,sum); k3_fin merges the lh halves.
// ---------------------------------------------------------------------------
extern "C" __global__ __launch_bounds__(512)
void k2f(const unsigned short* __restrict__ qhi,
         const unsigned short* __restrict__ qlo,
         const float* __restrict__ desc,
         float* __restrict__ Opart, float* __restrict__ ms)
{
    __shared__ __align__(16) f32x4 scr[3][2][64];     // 6144 B
    __shared__ __align__(16) float p_lds2[16][24];    // 1536 B
    __shared__ float f_lds[2][16];                    // 128 B

    const int b = blockIdx.x, lh = blockIdx.y, t = threadIdx.x;
    const int w = t >> 6, L = t & 63;
    const int st = w & 1, kq = w >> 1;
    const int g = L >> 4, r16 = L & 15;
    const int slot = t % 96, sq = t / 96;    // PV mapping (sq==5 idle in PV)

    const float* dsrc = desc + ((size_t)b*NL + (size_t)lh*256)*NH;
    const int s_in = 16*st + r16;
    const size_t qrow = ((size_t)b*NS + (s_in < NS ? s_in : NS-1))*(size_t)NH;

    // ---- hoist q (hi/lo) for this wave's k-quarter into registers ----
    bf16x8 qhreg[6], qlreg[6];
    #pragma unroll
    for (int kb = 0; kb < 6; ++kb) {
        const int k0 = 192*kq + 32*kb + 8*g;
        qhreg[kb] = *(const bf16x8*)&qhi[qrow + k0];
        qlreg[kb] = *(const bf16x8*)&qlo[qrow + k0];
    }

    f32x4 acc4[4][2];
    #pragma unroll
    for (int j = 0; j < 4; ++j) {
        acc4[j][0] = (f32x4){0.f,0.f,0.f,0.f};
        acc4[j][1] = (f32x4){0.f,0.f,0.f,0.f};
    }
    float m_run = -1e30f, sum_run = 0.f;

    #pragma unroll 1
    for (int tt = 0; tt < 16; ++tt) {
        const float* tsrc = dsrc + (size_t)tt*16*NH;

        // ---- QK^T partial: k in [192kq,192kq+192); A from global f32 ----
        f32x4 Se = (f32x4){0.f,0.f,0.f,0.f};
        #pragma unroll
        for (int kb = 0; kb < 6; ++kb) {
            const int k0 = 192*kq + 32*kb;
            const float* arow = tsrc + (size_t)r16*NH + k0 + 8*g;
            const f32x4 A0 = *(const f32x4*)&arow[0];
            const f32x4 A1 = *(const f32x4*)&arow[4];
            ushort4v h0, h1, l0, l1;
            #pragma unroll
            for (int e = 0; e < 4; ++e) {
                const float x0 = A0[e], x1 = A1[e];
                const unsigned short hh0 = bf16_rne(x0);
                const unsigned short hh1 = bf16_rne(x1);
                h0[e] = hh0;  h1[e] = hh1;
                l0[e] = bf16_rne(x0 - bf16f(hh0));
                l1[e] = bf16_rne(x1 - bf16f(hh1));
            }
            const bf16x8 Ah = __builtin_bit_cast(bf16x8,
                __builtin_shufflevector(h0, h1, 0,1,2,3,4,5,6,7));
            const bf16x8 Al = __builtin_bit_cast(bf16x8,
                __builtin_shufflevector(l0, l1, 0,1,2,3,4,5,6,7));
            Se = MFMA16(Ah, qhreg[kb], Se, 0,0,0);
            Se = MFMA16(Al, qhreg[kb], Se, 0,0,0);
            Se = MFMA16(Ah, qlreg[kb], Se, 0,0,0);
        }
        if (kq > 0) scr[kq-1][st][L] = Se;
        bar_lds();   // B2: partials ready

        // ---- kq==0 waves: reduce + online softmax ----
        if (kq == 0) {
            Se += scr[0][st][L];
            Se += scr[1][st][L];
            Se += scr[2][st][L];
            // lane holds S[l = 4g+r][s = 16st + r16]
            float pm = fmaxf(fmaxf(Se[0],Se[1]), fmaxf(Se[2],Se[3]));
            pm = fmaxf(pm, __shfl_xor(pm, 16));
            pm = fmaxf(pm, __shfl_xor(pm, 32));
            const float mnew = fmaxf(m_run, pm);
            const float fsc  = __expf(m_run - mnew);
            float pe[4];
            #pragma unroll
            for (int r = 0; r < 4; ++r) pe[r] = __expf(Se[r] - mnew);
            float ts = (pe[0]+pe[1]) + (pe[2]+pe[3]);
            ts += __shfl_xor(ts, 16);
            ts += __shfl_xor(ts, 32);
            sum_run = sum_run*fsc + ts;
            m_run = mnew;
            if (s_in < NS) {           // clamp lanes must not write (R14 fix)
                #pragma unroll
                for (int r = 0; r < 4; ++r)
                    p_lds2[4*g + r][s_in] = pe[r];
            }
            if (L < 16) f_lds[st][L] = fsc;
        }
        bar_lds();   // B3: p_lds2/f_lds ready

        // ---- PV (f32 exact, desc from global L2-hot) ----
        if (sq < 5) {
            #pragma unroll
            for (int j = 0; j < 4; ++j) {
                const int s = 4*sq + j;
                const float f = f_lds[s>>4][s&15];
                acc4[j][0] *= f;  acc4[j][1] *= f;
            }
            #pragma unroll 4
            for (int l = 0; l < 16; ++l) {
                const float* drow = tsrc + (size_t)l*NH;
                const f32x4 d0 = *(const f32x4*)&drow[4*slot];
                const f32x4 d1 = *(const f32x4*)&drow[384 + 4*slot];
                const f32x4 pv = *(const f32x4*)&p_lds2[l][4*sq];
                acc4[0][0] += pv[0] * d0;  acc4[0][1] += pv[0] * d1;
                acc4[1][0] += pv[1] * d0;  acc4[1][1] += pv[1] * d1;
                acc4[2][0] += pv[2] * d0;  acc4[2][1] += pv[2] * d1;
                acc4[3][0] += pv[3] * d0;  acc4[3][1] += pv[3] * d1;
            }
        }
    }

    // ---- epilogue: write 1/sum, then store per-half-normalized partials ----
    bar_lds();
    if (kq == 0 && L < 16) f_lds[st][L] = 1.0f / sum_run;
    bar_lds();
    if (sq < 5) {
        #pragma unroll
        for (int j = 0; j < 4; ++j) {
            const int s = 4*sq + j;
            const float inv = f_lds[s>>4][s&15];
            float* Ob = Opart + ((size_t)(b*2 + lh)*NS + s)*NH;
            f32x4 o0 = acc4[j][0], o1 = acc4[j][1];
            o0 *= inv;  o1 *= inv;
            *(f32x4*)&Ob[4*slot]       = o0;
            *(f32x4*)&Ob[384 + 4*slot] = o1;
        }
    }
    if (kq == 0 && L < 16) {
        const int s2 = 16*st + L;
        if (s2 < NS) {
            ms[((size_t)(b*2 + lh)*NS + s2)*2 + 0] = m_run;
            ms[((size_t)(b*2 + lh)*NS + s2)*2 + 1] = sum_run;
        }
    }
}

// ---------------------------------------------------------------------------
// K3: merge the two l-half partials per (b,s).  Each half's O is normalized
// by its own sum; recombine with softmax-of-(m,sum) weights:
//   out = c0*O0 + c1*O1,  c_i = e^{m_i-m} s_i / (e^{m0-m}s0 + e^{m1-m}s1)
// ---------------------------------------------------------------------------
extern "C" __global__ __launch_bounds__(256)
void k3_fin(const float* __restrict__ Opart, const float* __restrict__ ms,
            float* __restrict__ out)
{
    __shared__ float c0s[NS], c1s[NS];
    const int b = blockIdx.x, t = threadIdx.x;
    if (t < NS) {
        const float m0 = ms[((size_t)(b*2 + 0)*NS + t)*2 + 0];
        const float s0 = ms[((size_t)(b*2 + 0)*NS + t)*2 + 1];
        const float m1 = ms[((size_t)(b*2 + 1)*NS + t)*2 + 0];
        const float s1 = ms[((size_t)(b*2 + 1)*NS + t)*2 + 1];
        const float m  = fmaxf(m0, m1);
        const float w0 = __expf(m0 - m)*s0, w1 = __expf(m1 - m)*s1;
        const float inv = 1.0f / (w0 + w1);
        c0s[t] = w0*inv;
        c1s[t] = w1*inv;
    }
    __syncthreads();
    const float* O0 = Opart + (size_t)(b*2 + 0)*NS*NH;
    const float* O1 = Opart + (size_t)(b*2 + 1)*NS*NH;
    #pragma unroll 1
    for (int i4 = t; i4 < NS*NH/4; i4 += 256) {
        const int idx = 4*i4;
        const int s = idx / NH, h = idx - s*NH;
        const f32x4 a = *(const f32x4*)&O0[idx];
        const f32x4 c = *(const f32x4*)&O1[idx];
        const float c0 = c0s[s], c1 = c1s[s];
        f32x4 o;
        o[0] = c0*a[0] + c1*c[0]; o[1] = c0*a[1] + c1*c[1];
        o[2] = c0*a[2] + c1*c[2]; o[3] = c0*a[3] + c1*c[3];
        *(f32x4*)&out[(size_t)b*ROWE + (size_t)s*(ND+NH) + ND + h] = o;
    }
}

// ---------------------------------------------------------------------------
extern "C" void kernel_launch(void* const* d_in, const int* in_sizes, int n_in,
                              void* d_out, int out_size, void* d_ws, size_t ws_size,
                              hipStream_t stream)
{
    const int*   skills = (const int*)  d_in[0];
    const float* desc   = (const float*)d_in[1];
    const float* embs   = (const float*)d_in[2];
    const float* W      = (const float*)d_in[3];
    float* out = (float*)d_out;

    unsigned short* qhi = (unsigned short*)d_ws;          // [NB][NS][NH] bf16
    unsigned short* qlo = qhi + (size_t)NB*NS*NH;         // [NB][NS][NH] bf16
    float* Opart = (float*)(qlo + (size_t)NB*NS*NH);      // [NB*2][NS][NH] f32
    float* ms    = Opart + (size_t)NB*2*NS*NH;            // [NB*2][NS][2]  f32

    k1_q  <<<NB,          256, 0, stream>>>(skills, embs, W, qhi, qlo, out);
    k2f   <<<dim3(NB, 2), 512, 0, stream>>>(qhi, qlo, desc, Opart, ms);
    k3_fin<<<NB,          256, 0, stream>>>(Opart, ms, out);
}

// Round 18
// 236.910 us; speedup vs baseline: 1.2205x; 1.2205x over previous
//
#include <hip/hip_runtime.h>
#include <cstddef>
#include <cstdint>

#define NB 256
#define NS 20
#define NL 512
#define ND 128
#define NH 768
#define ROWE (NS*(ND+NH))   // 17920 floats per output row

typedef __attribute__((ext_vector_type(4))) float  f32x4;
typedef __attribute__((ext_vector_type(8))) short  bf16x8;
typedef __attribute__((ext_vector_type(4))) short  short4v;
typedef __attribute__((ext_vector_type(4))) unsigned short ushort4v;
typedef __attribute__((ext_vector_type(8))) unsigned short ushort8v;

#define MFMA16 __builtin_amdgcn_mfma_f32_16x16x32_bf16

#if defined(__has_builtin)
#  if __has_builtin(__builtin_amdgcn_mfma_f32_16x16x16bf16_1k)
#    define MFMA_PV(a,b,c) __builtin_amdgcn_mfma_f32_16x16x16bf16_1k(a,b,c,0,0,0)
#  elif __has_builtin(__builtin_amdgcn_mfma_f32_16x16x16_bf16)
#    define MFMA_PV(a,b,c) __builtin_amdgcn_mfma_f32_16x16x16_bf16(a,b,c,0,0,0)
#  endif
#endif

__device__ __forceinline__ unsigned short bf16_rne(float v){
    unsigned u = __builtin_bit_cast(unsigned, v);
    u = (u + 0x7fffu + ((u>>16)&1u)) >> 16;
    return (unsigned short)u;
}
__device__ __forceinline__ float bf16f(unsigned short h){
    unsigned u = ((unsigned)h)<<16;
    return __builtin_bit_cast(float, u);
}
// LDS-only barrier (no vmcnt drain): global loads/DMA stay in flight.
__device__ __forceinline__ void bar_lds(){
    asm volatile("s_waitcnt lgkmcnt(0)" ::: "memory");
    __builtin_amdgcn_s_barrier();
}

// ---------------------------------------------------------------------------
// K1: se = embs[skills[b]] -> out (concat left part);  q = se @ W -> bf16
// hi/lo arrays in ws. 256 blocks x 256 threads; wave w owns s in [5w,5w+5).
// ---------------------------------------------------------------------------
extern "C" __global__ __launch_bounds__(256)
void k1_q(const int* __restrict__ skills, const float* __restrict__ embs,
          const float* __restrict__ W,
          unsigned short* __restrict__ qhi, unsigned short* __restrict__ qlo,
          float* __restrict__ out)
{
    __shared__ float se[NS*ND];
    __shared__ int   sk[NS];
    const int b = blockIdx.x, t = threadIdx.x;
    if (t < NS) sk[t] = skills[b*NS + t];
    __syncthreads();
    for (int idx = t; idx < NS*ND; idx += 256) {
        const int s = idx >> 7, d = idx & (ND-1);
        const float v = embs[(size_t)sk[s]*ND + d];
        se[idx] = v;
        out[(size_t)b*ROWE + (size_t)s*(ND+NH) + d] = v;
    }
    __syncthreads();

    const int w = t >> 6, lane = t & 63;
    float acc[5][12];
    #pragma unroll
    for (int i = 0; i < 5; ++i)
        #pragma unroll
        for (int c = 0; c < 12; ++c) acc[i][c] = 0.f;

    const float* Wl = W + lane;
    for (int d4 = 0; d4 < ND/4; ++d4) {
        f32x4 sv[5];
        #pragma unroll
        for (int i = 0; i < 5; ++i)
            sv[i] = *(const f32x4*)&se[(5*w + i)*ND + 4*d4];
        #pragma unroll
        for (int r = 0; r < 4; ++r) {
            const float* wr = Wl + (size_t)(4*d4 + r)*NH;
            float wv[12];
            #pragma unroll
            for (int c = 0; c < 12; ++c) wv[c] = wr[64*c];
            #pragma unroll
            for (int i = 0; i < 5; ++i) {
                const float s_ = sv[i][r];
                #pragma unroll
                for (int c = 0; c < 12; ++c) acc[i][c] += s_*wv[c];
            }
        }
    }
    #pragma unroll
    for (int i = 0; i < 5; ++i)
        #pragma unroll
        for (int c = 0; c < 12; ++c) {
            const size_t idx = ((size_t)b*NS + 5*w + i)*NH + lane + 64*c;
            const float v = acc[i][c];
            const unsigned short hh = bf16_rne(v);
            qhi[idx] = hh;
            qlo[idx] = bf16_rne(v - bf16f(hh));
        }
}

// ---------------------------------------------------------------------------
// K2F: fused flash partial over an l-range of 256.  Grid (NB,2) split by l.
// 512 threads (8 waves); QK roles: st = w&1 (s-tile), kq = w>>1 (k-quarter).
//
// R18: dt = RAW F32 tile staged by global_load_lds DMA (no staging VALU, no
// sreg regs; R16-verified addressing).  DMA(t+1) issued at B2 (dt dead after
// QK), waited at next tile top — flight covered by softmax+vt+PV and the
// co-resident block.  QK converts hi/lo in-register (R16-proven).  PV = MFMA
// 16x16x16 bf16 (K=16 == tile rows, no padding): O^T = V^T x P^T, A from
// vt[768][16] (transposed tile, built by L2-hot global gather), B from
// p_lds2 bf16.  PV/wave: 8 b64 reads + 12 MFMA (was 48 b128 + 512 VALU).
// LDS 76.2 KB -> 2 blocks/CU.  4 LDS-only barriers + 1 vmcnt top-wait.
// Outputs UNNORMALIZED Opart + (m,sum); k3_fin merges the lh halves.
// ---------------------------------------------------------------------------
#define DTFP  772                 // f32 row pitch
#define CPR   193                 // 16B-chunks per row (772*4/16)

extern "C" __global__ __launch_bounds__(512)
void k2f(const unsigned short* __restrict__ qhi,
         const unsigned short* __restrict__ qlo,
         const float* __restrict__ desc,
         float* __restrict__ Opart, float* __restrict__ ms)
{
    __shared__ __align__(16) float dtf[12544];              // 50176 B
    __shared__ __align__(16) unsigned short vt[768*16];     // 24576 B (+scr ovl)
    __shared__ __align__(16) unsigned short p_lds2[2][16][20]; // 1280 B
    __shared__ float f_lds[2][16];                          // 128 B

    const int b = blockIdx.x, lh = blockIdx.y, t = threadIdx.x;
    const int w = t >> 6, L = t & 63;
    const int st = w & 1, kq = w >> 1;
    const int g = L >> 4, r16 = L & 15;

    const float* dsrc = desc + ((size_t)b*NL + (size_t)lh*256)*NH;
    const int s_in = 16*st + r16;
    const size_t qrow = ((size_t)b*NS + (s_in < NS ? s_in : NS-1))*(size_t)NH;

    // ---- hoist q (hi/lo) for this wave's k-quarter into registers ----
    bf16x8 qhreg[6], qlreg[6];
    #pragma unroll
    for (int kb = 0; kb < 6; ++kb) {
        const int k0 = 192*kq + 32*kb + 8*g;
        qhreg[kb] = *(const bf16x8*)&qhi[qrow + k0];
        qlreg[kb] = *(const bf16x8*)&qlo[qrow + k0];
    }

    // acc[2*hti + st2] = O^T tile (ht = w + 8*hti, s-tile st2)
    f32x4 acc[12];
    #pragma unroll
    for (int i = 0; i < 12; ++i) acc[i] = (f32x4){0.f,0.f,0.f,0.f};
    float m_run = -1e30f, sum_run = 0.f;

    // ---- DMA: stage 16x768 f32 tile into padded-pitch LDS (R16-verified) --
    auto issue_dma = [&](const float* tsrc){
        #pragma unroll
        for (int i = 0; i < 6; ++i) {
            const int ch = 8*i + w;
            const unsigned s = (unsigned)(ch*64 + L);
            unsigned row = (s*5434u) >> 20;
            unsigned col = s - row*CPR;
            if (row > 15u) row = 15u;
            if (col > 191u) col = 191u;
            const float* gsrc = tsrc + (size_t)row*NH + 4u*col;
            __builtin_amdgcn_global_load_lds(gsrc, &dtf[ch*256], 16, 0, 0);
        }
        if (w == 0) {
            const unsigned s = (unsigned)(48*64 + L);
            unsigned row = (s*5434u) >> 20;
            unsigned col = s - row*CPR;
            if (row > 15u) row = 15u;
            if (col > 191u) col = 191u;
            const float* gsrc = tsrc + (size_t)row*NH + 4u*col;
            __builtin_amdgcn_global_load_lds(gsrc, &dtf[48*256], 16, 0, 0);
        }
    };

    issue_dma(dsrc);   // prologue: tile 0

    #pragma unroll 1
    for (int tt = 0; tt < 16; ++tt) {
        asm volatile("s_waitcnt vmcnt(0)" ::: "memory");   // DMA(tt) landed
        bar_lds();   // top: dtf ready; prior PV done with vt

        // ---- QK^T partial: k in [192kq,192kq+192); A built from f32 ----
        f32x4 Se = (f32x4){0.f,0.f,0.f,0.f};
        #pragma unroll
        for (int kb = 0; kb < 6; ++kb) {
            const int k0 = 192*kq + 32*kb;
            const float* arow = &dtf[r16*DTFP + k0 + 8*g];
            const f32x4 A0 = *(const f32x4*)&arow[0];
            const f32x4 A1 = *(const f32x4*)&arow[4];
            ushort4v h0, h1, l0, l1;
            #pragma unroll
            for (int e = 0; e < 4; ++e) {
                const float x0 = A0[e], x1 = A1[e];
                const unsigned short hh0 = bf16_rne(x0);
                const unsigned short hh1 = bf16_rne(x1);
                h0[e] = hh0;  h1[e] = hh1;
                l0[e] = bf16_rne(x0 - bf16f(hh0));
                l1[e] = bf16_rne(x1 - bf16f(hh1));
            }
            const bf16x8 Ah = __builtin_bit_cast(bf16x8,
                __builtin_shufflevector(h0, h1, 0,1,2,3,4,5,6,7));
            const bf16x8 Al = __builtin_bit_cast(bf16x8,
                __builtin_shufflevector(l0, l1, 0,1,2,3,4,5,6,7));
            Se = MFMA16(Ah, qhreg[kb], Se, 0,0,0);
            Se = MFMA16(Al, qhreg[kb], Se, 0,0,0);
            Se = MFMA16(Ah, qlreg[kb], Se, 0,0,0);
        }
        {   // scr overlay lives at the base of vt
            f32x4* scr = (f32x4*)vt;
            if (kq > 0) scr[((kq-1)*2 + st)*64 + L] = Se;
        }
        bar_lds();   // B2: QK done reading dtf; partials ready

        // ---- dtf free: issue next tile's DMA (in flight across sm+vt+PV) --
        if (tt < 15) issue_dma(dsrc + (size_t)(tt+1)*16*NH);

        // ---- vt gather: tile rows re-read from global (L2-hot), -> bf16 ----
        ushort8v v0bf[3];
        {
            const float* tsrc = dsrc + (size_t)tt*16*NH;
            #pragma unroll
            for (int rep = 0; rep < 3; ++rep) {
                const int u = 512*rep + t;
                const int h = u >> 1, half = u & 1;
                const float* gs = tsrc + (size_t)(8*half)*NH + h;
                #pragma unroll
                for (int e = 0; e < 8; ++e)
                    v0bf[rep][e] = bf16_rne(gs[(size_t)e*NH]);
            }
        }

        // ---- kq==0 waves: reduce partials + online softmax ----
        if (kq == 0) {
            const f32x4* scr = (const f32x4*)vt;
            Se += scr[(0*2 + st)*64 + L];
            Se += scr[(1*2 + st)*64 + L];
            Se += scr[(2*2 + st)*64 + L];
            // lane holds S[l = 4g+r][s = 16st + r16]
            float pm = fmaxf(fmaxf(Se[0],Se[1]), fmaxf(Se[2],Se[3]));
            pm = fmaxf(pm, __shfl_xor(pm, 16));
            pm = fmaxf(pm, __shfl_xor(pm, 32));
            const float mnew = fmaxf(m_run, pm);
            const float fsc  = __expf(m_run - mnew);
            float pe[4];
            #pragma unroll
            for (int r = 0; r < 4; ++r) pe[r] = __expf(Se[r] - mnew);
            float ts = (pe[0]+pe[1]) + (pe[2]+pe[3]);
            ts += __shfl_xor(ts, 16);
            ts += __shfl_xor(ts, 32);
            sum_run = sum_run*fsc + ts;
            m_run = mnew;
            if (s_in < NS) {           // clamp lanes must not write (R14 fix)
                #pragma unroll
                for (int r = 0; r < 4; ++r)
                    p_lds2[st][r16][4*g + r] = bf16_rne(pe[r]);
            }
            if (L < 16) f_lds[st][L] = fsc;
        }
        bar_lds();   // B3: p/f ready; scr reads done -> vt region writable

        // ---- vt writes: transposed tile vt[h][l] (b128, aligned) ----
        #pragma unroll
        for (int rep = 0; rep < 3; ++rep) {
            const int u = 512*rep + t;
            const int h = u >> 1, half = u & 1;
            *(ushort8v*)&vt[h*16 + 8*half] = v0bf[rep];
        }
        bar_lds();   // B4: vt ready

        // ---- PV: O^T = V^T x P^T, K=16 MFMA (or VALU fallback) ----
        const float f0 = f_lds[0][r16], f1 = f_lds[1][r16];
        #pragma unroll
        for (int i = 0; i < 12; ++i) {
            const float ff = (i & 1) ? f1 : f0;
            acc[i][0]*=ff; acc[i][1]*=ff; acc[i][2]*=ff; acc[i][3]*=ff;
        }
#ifdef MFMA_PV
        const short4v pb0 = *(const short4v*)&p_lds2[0][r16][4*g];
        const short4v pb1 = *(const short4v*)&p_lds2[1][r16][4*g];
        #pragma unroll
        for (int hti = 0; hti < 6; ++hti) {
            const int hrow = 16*(w + 8*hti) + r16;      // A row m = r16
            const short4v av = *(const short4v*)&vt[hrow*16 + 4*g];
            acc[2*hti+0] = MFMA_PV(av, pb0, acc[2*hti+0]);
            acc[2*hti+1] = MFMA_PV(av, pb1, acc[2*hti+1]);
        }
#else
        // VALU fallback: same acc layout, per-lane dot products
        #pragma unroll
        for (int hti = 0; hti < 6; ++hti) {
            const int hb = 16*(w + 8*hti) + 4*g;
            #pragma unroll
            for (int st2 = 0; st2 < 2; ++st2) {
                f32x4 a = acc[2*hti+st2];
                #pragma unroll
                for (int l = 0; l < 16; ++l) {
                    const float pl = bf16f(p_lds2[st2][r16][l]);
                    #pragma unroll
                    for (int j = 0; j < 4; ++j)
                        a[j] += pl * bf16f(vt[(hb + j)*16 + l]);
                }
                acc[2*hti+st2] = a;
            }
        }
#endif
    }

    // ---- epilogue: write 1/sum, then store per-half-normalized partials ----
    bar_lds();
    if (kq == 0 && L < 16) f_lds[st][L] = 1.0f / sum_run;
    bar_lds();
    {
        const float i0 = f_lds[0][r16], i1 = f_lds[1][r16];
        float* Ob = Opart + (size_t)(b*2 + lh)*NS*NH;
        #pragma unroll
        for (int hti = 0; hti < 6; ++hti) {
            const int ht = w + 8*hti;
            #pragma unroll
            for (int st2 = 0; st2 < 2; ++st2) {
                const int s = 16*st2 + r16;
                if (s < NS) {
                    const float inv = st2 ? i1 : i0;
                    f32x4 o = acc[2*hti+st2];
                    o[0]*=inv; o[1]*=inv; o[2]*=inv; o[3]*=inv;
                    // D row m = 4g+j -> h = 16*ht + 4g + j (j contiguous)
                    *(f32x4*)&Ob[(size_t)s*NH + 16*ht + 4*g] = o;
                }
            }
        }
    }
    if (kq == 0 && L < 16) {
        const int s2 = 16*st + L;
        if (s2 < NS) {
            ms[((size_t)(b*2 + lh)*NS + s2)*2 + 0] = m_run;
            ms[((size_t)(b*2 + lh)*NS + s2)*2 + 1] = sum_run;
        }
    }
}

// ---------------------------------------------------------------------------
// K3: merge the two l-half partials per (b,s).  Each half's O is normalized
// by its own sum; recombine with softmax-of-(m,sum) weights:
//   out = c0*O0 + c1*O1,  c_i = e^{m_i-m} s_i / (e^{m0-m}s0 + e^{m1-m}s1)
// ---------------------------------------------------------------------------
extern "C" __global__ __launch_bounds__(256)
void k3_fin(const float* __restrict__ Opart, const float* __restrict__ ms,
            float* __restrict__ out)
{
    __shared__ float c0s[NS], c1s[NS];
    const int b = blockIdx.x, t = threadIdx.x;
    if (t < NS) {
        const float m0 = ms[((size_t)(b*2 + 0)*NS + t)*2 + 0];
        const float s0 = ms[((size_t)(b*2 + 0)*NS + t)*2 + 1];
        const float m1 = ms[((size_t)(b*2 + 1)*NS + t)*2 + 0];
        const float s1 = ms[((size_t)(b*2 + 1)*NS + t)*2 + 1];
        const float m  = fmaxf(m0, m1);
        const float w0 = __expf(m0 - m)*s0, w1 = __expf(m1 - m)*s1;
        const float inv = 1.0f / (w0 + w1);
        c0s[t] = w0*inv;
        c1s[t] = w1*inv;
    }
    __syncthreads();
    const float* O0 = Opart + (size_t)(b*2 + 0)*NS*NH;
    const float* O1 = Opart + (size_t)(b*2 + 1)*NS*NH;
    #pragma unroll 1
    for (int i4 = t; i4 < NS*NH/4; i4 += 256) {
        const int idx = 4*i4;
        const int s = idx / NH, h = idx - s*NH;
        const f32x4 a = *(const f32x4*)&O0[idx];
        const f32x4 c = *(const f32x4*)&O1[idx];
        const float c0 = c0s[s], c1 = c1s[s];
        f32x4 o;
        o[0] = c0*a[0] + c1*c[0]; o[1] = c0*a[1] + c1*c[1];
        o[2] = c0*a[2] + c1*c[2]; o[3] = c0*a[3] + c1*c[3];
        *(f32x4*)&out[(size_t)b*ROWE + (size_t)s*(ND+NH) + ND + h] = o;
    }
}

// ---------------------------------------------------------------------------
extern "C" void kernel_launch(void* const* d_in, const int* in_sizes, int n_in,
                              void* d_out, int out_size, void* d_ws, size_t ws_size,
                              hipStream_t stream)
{
    const int*   skills = (const int*)  d_in[0];
    const float* desc   = (const float*)d_in[1];
    const float* embs   = (const float*)d_in[2];
    const float* W      = (const float*)d_in[3];
    float* out = (float*)d_out;

    unsigned short* qhi = (unsigned short*)d_ws;          // [NB][NS][NH] bf16
    unsigned short* qlo = qhi + (size_t)NB*NS*NH;         // [NB][NS][NH] bf16
    float* Opart = (float*)(qlo + (size_t)NB*NS*NH);      // [NB*2][NS][NH] f32
    float* ms    = Opart + (size_t)NB*2*NS*NH;            // [NB*2][NS][2]  f32

    k1_q  <<<NB,          256, 0, stream>>>(skills, embs, W, qhi, qlo, out);
    k2f   <<<dim3(NB, 2), 512, 0, stream>>>(qhi, qlo, desc, Opart, ms);
    k3_fin<<<NB,          256, 0, stream>>>(Opart, ms, out);
}